// Round 1
// baseline (101.642 us; speedup 1.0000x reference)
//
#include <hip/hip_runtime.h>

#define THREADS 256

// Problem constants
#define IN_C 32
#define OUT_C 64
#define HW 64
#define Q_N 36
#define P_N 8
#define MB 8

__global__ __launch_bounds__(THREADS)
void morr_conv_kernel(const float* __restrict__ x,
                      const float* __restrict__ weight,
                      const float* __restrict__ mos,
                      float* __restrict__ out)
{
    // LDS: input tile (32 ch x 10 x 10, plane padded to 101), weights, scale
    __shared__ float sx[IN_C * 101];      // 12.9 KB
    __shared__ float wlds[P_N * Q_N * MB]; // 9.2 KB
    __shared__ float slds[Q_N];

    const int tid = threadIdx.x;
    const int blk = blockIdx.x;
    const int b    = blk >> 6;       // image
    const int tile = blk & 63;       // 8x8 tiles of 8x8 pixels
    const int ty = tile >> 3, tx = tile & 7;
    const int h0 = ty * 8, w0 = tx * 8;

    const float GAIN = 1.6666666666666667f;   // sqrt(100/36)... = 10/6 applied to x^2

    // ---- stage squared input tile (with halo, zero padded) ----
    for (int idx = tid; idx < 3200; idx += THREADS) {
        int c   = idx / 100;
        int rem = idx - c * 100;
        int h   = rem / 10;
        int w   = rem - h * 10;
        int gh = h0 + h - 1;
        int gw = w0 + w - 1;
        float v = 0.f;
        if ((unsigned)gh < 64u && (unsigned)gw < 64u)
            v = x[((b * IN_C + c) * HW + gh) * HW + gw];
        sx[c * 101 + h * 10 + w] = GAIN * v * v;
    }
    // ---- stage weights (P,Q,MB flat) ----
    for (int idx = tid; idx < P_N * Q_N * MB; idx += THREADS)
        wlds[idx] = weight[idx];
    // ---- stage signed scale: q<18 -> +mos[q], q>=18 -> -mos[q-18] ----
    if (tid < Q_N)
        slds[tid] = (tid < 18) ? mos[tid] : -mos[tid - 18];
    __syncthreads();

    const int pg  = tid & 3;     // which pair of p-blocks this thread owns
    const int pix = tid >> 2;    // 0..63 pixel within tile
    const int px = pix & 7, py = pix >> 3;

    // mrr_tr constants
    const float A_ = 0.8578f, R_ = 0.8985f;
    const float S_ = A_ * A_ + R_ * R_;          // A^2+R^2
    const float D_ = 1.f + (A_ * R_) * (A_ * R_);
    const float C2 = 2.f * A_ * R_;

    float acc[16];
#pragma unroll
    for (int i = 0; i < 16; ++i) acc[i] = 0.f;

    const int dbase = py * 10 + px;

    // 288 im2col entries = 4 super-periods of 72 (lcm(8,9)); inside a period
    // all /9, %9, /3, %3 are compile-time after unrolling.
#pragma unroll 1
    for (int z = 0; z < 4; ++z) {
        const int sbase = (z * 8) * 101 + dbase;  // channel base z*8
        const int qz = z * 9;
#pragma unroll
        for (int qi = 0; qi < 9; ++qi) {
            float iv[8];
#pragma unroll
            for (int j = 0; j < 8; ++j) {
                const int u  = qi * 8 + j;     // 0..71 (compile-time)
                const int cu = u / 9;
                const int r  = u - cu * 9;
                const int ki = r / 3;
                const int kj = r - ki * 3;
                iv[j] = sx[sbase + cu * 101 + ki * 10 + kj];
            }
            const float sc = slds[qz + qi];
#pragma unroll
            for (int pi = 0; pi < 2; ++pi) {
                const int p  = pg * 2 + pi;
                const int wb = p * (Q_N * MB) + (qz + qi) * MB;
                float wv[8];
#pragma unroll
                for (int m = 0; m < 8; ++m) wv[m] = wlds[wb + m];
                float ph[8];
#pragma unroll
                for (int k = 0; k < 8; ++k) ph[k] = 0.f;
#pragma unroll
                for (int j = 0; j < 8; ++j) {
#pragma unroll
                    for (int k = 0; k < 8; ++k) {
                        ph[k] = fmaf(iv[j], wv[(k - j) & 7], ph[k]);
                    }
                }
#pragma unroll
                for (int k = 0; k < 8; ++k) {
                    float c  = C2 * __cosf(ph[k]);
                    float tr = (S_ - c) * __builtin_amdgcn_rcpf(D_ - c);
                    acc[pi * 8 + k] = fmaf(sc, tr, acc[pi * 8 + k]);
                }
            }
        }
    }

    // ---- store: oc = pg*16 + pi*8 + k ----
    const int ho = h0 + py, wo = w0 + px;
    float* op = out + ((b * OUT_C + pg * 16) * HW + ho) * HW + wo;
#pragma unroll
    for (int pi = 0; pi < 2; ++pi) {
#pragma unroll
        for (int k = 0; k < 8; ++k) {
            op[(pi * 8 + k) * (HW * HW)] = acc[pi * 8 + k];
        }
    }
}

extern "C" void kernel_launch(void* const* d_in, const int* in_sizes, int n_in,
                              void* d_out, int out_size, void* d_ws, size_t ws_size,
                              hipStream_t stream) {
    const float* x      = (const float*)d_in[0];
    const float* weight = (const float*)d_in[1];
    const float* mos    = (const float*)d_in[2];
    float* out = (float*)d_out;

    // 8 images x 64 tiles (8x8 grid of 8x8-pixel tiles)
    dim3 grid(512), block(THREADS);
    hipLaunchKernelGGL(morr_conv_kernel, grid, block, 0, stream, x, weight, mos, out);
}

// Round 2
// 96.106 us; speedup vs baseline: 1.0576x; 1.0576x over previous
//
#include <hip/hip_runtime.h>

#define THREADS 256

#define IN_C 32
#define OUT_C 64
#define HW 64
#define Q_N 36
#define P_N 8
#define MB 8

// sx plane: 3 rows x 34 cols per channel
#define SXPLANE 102
// weight LDS: [q][p][8]
#define W2SZ (Q_N * P_N * MB)

__global__ __launch_bounds__(THREADS, 4)
void morr_conv_kernel(const float* __restrict__ x,
                      const float* __restrict__ weight,
                      const float* __restrict__ mos,
                      float* __restrict__ out)
{
    __shared__ float sx[IN_C * SXPLANE];   // 32ch x 3rows x 34cols = 13.1 KB
    __shared__ float w2[W2SZ];             // [q][p][m], 9.2 KB
    __shared__ float slds[Q_N];

    const int tid = threadIdx.x;
    const int blk = blockIdx.x;
    const int b   = blk >> 7;          // image
    const int tile = blk & 127;        // 64 rows x 2 col-tiles
    const int row = tile >> 1;
    const int w0  = (tile & 1) << 5;   // 0 or 32

    const float GAIN    = 1.6666666666666667f;          // sqrt(100/36)
    const float INV2PI  = 0.15915494309189535f;

    // ---- stage squared input rows (row-1, row, row+1), cols w0-1..w0+32 ----
    for (int idx = tid; idx < IN_C * SXPLANE; idx += THREADS) {
        int c   = idx / SXPLANE;
        int rem = idx - c * SXPLANE;
        int r   = rem / 34;            // 0..2
        int col = rem - r * 34;        // 0..33
        int gh = row + r - 1;
        int gw = w0 + col - 1;
        float v = 0.f;
        if ((unsigned)gh < 64u && (unsigned)gw < 64u)
            v = x[((b * IN_C + c) * HW + gh) * HW + gw];
        sx[idx] = GAIN * v * v;
    }
    // ---- stage weights as [q][p][m], folded by 1/(2*pi) ----
    for (int idx = tid; idx < W2SZ; idx += THREADS) {
        int p   = idx / (Q_N * MB);
        int rem = idx - p * (Q_N * MB);
        int q   = rem >> 3;
        int m   = idx & 7;
        w2[(q * P_N + p) * MB + m] = weight[idx] * INV2PI;
    }
    // ---- signed scale ----
    if (tid < Q_N)
        slds[tid] = (tid < 18) ? mos[tid] : -mos[tid - 18];
    __syncthreads();

    const int px = tid & 31;    // pixel column within 32-wide tile
    const int p  = tid >> 5;    // output channel-block 0..7

    // tr(phi) = (S - c)/(D - c) = 1 + E/(D - c),  c = C2*cos(phi)
    // sum_q sc_q = 0 exactly (Q even) -> out = E * sum_q sc_q * rcp(D - c)
    const float A_ = 0.8578f, R_ = 0.8985f;
    const float S_ = A_ * A_ + R_ * R_;
    const float D_ = 1.f + (A_ * R_) * (A_ * R_);
    const float C2 = 2.f * A_ * R_;
    const float E_ = S_ - D_;

    float acc[8];
#pragma unroll
    for (int i = 0; i < 8; ++i) acc[i] = 0.f;

    const float4* w4 = (const float4*)w2;

#pragma unroll 1
    for (int z = 0; z < 4; ++z) {
        const int sbase = (z * 8) * SXPLANE + px;   // channel base z*8, this pixel
        const int qz = z * 9;
#pragma unroll
        for (int qi = 0; qi < 9; ++qi) {
            // im2col gather: u = qi*8+j in [0,72), cu = u/9, r = u%9
            float iv[8];
#pragma unroll
            for (int j = 0; j < 8; ++j) {
                const int u  = qi * 8 + j;
                const int cu = u / 9;
                const int r  = u - cu * 9;
                const int ki = r / 3;
                const int kj = r - ki * 3;
                iv[j] = sx[sbase + cu * SXPLANE + ki * 34 + kj];
            }
            const float sc = slds[qz + qi];
            // weights for (q, p): 8 floats = 2x float4, conflict-free
            const int wq = ((qz + qi) * P_N + p) * 2;
            float4 wlo = w4[wq], whi = w4[wq + 1];
            float wv[8] = {wlo.x, wlo.y, wlo.z, wlo.w, whi.x, whi.y, whi.z, whi.w};

            float ph[8];
#pragma unroll
            for (int k = 0; k < 8; ++k) ph[k] = iv[0] * wv[k];
#pragma unroll
            for (int j = 1; j < 8; ++j) {
#pragma unroll
                for (int k = 0; k < 8; ++k)
                    ph[k] = fmaf(iv[j], wv[(k - j) & 7], ph[k]);
            }
#pragma unroll
            for (int k = 0; k < 8; ++k) {
                float cc = __builtin_amdgcn_cosf(ph[k]);       // phi in revolutions
                float d  = fmaf(-C2, cc, D_);
                float r_ = __builtin_amdgcn_rcpf(d);
                acc[k] = fmaf(sc, r_, acc[k]);
            }
        }
    }

    // ---- store: oc = p*8 + k, pixel = row*64 + w0 + px ----
    float* op = out + ((b * OUT_C + p * MB) * (HW * HW)) + row * HW + w0 + px;
#pragma unroll
    for (int k = 0; k < 8; ++k)
        op[k * (HW * HW)] = E_ * acc[k];
}

extern "C" void kernel_launch(void* const* d_in, const int* in_sizes, int n_in,
                              void* d_out, int out_size, void* d_ws, size_t ws_size,
                              hipStream_t stream) {
    const float* x      = (const float*)d_in[0];
    const float* weight = (const float*)d_in[1];
    const float* mos    = (const float*)d_in[2];
    float* out = (float*)d_out;

    // 8 images x 64 rows x 2 col-tiles
    dim3 grid(1024), block(THREADS);
    hipLaunchKernelGGL(morr_conv_kernel, grid, block, 0, stream, x, weight, mos, out);
}

// Round 3
// 91.229 us; speedup vs baseline: 1.1141x; 1.0535x over previous
//
#include <hip/hip_runtime.h>

#define THREADS 256

#define IN_C 32
#define OUT_C 64
#define HW 64
#define Q_N 36
#define P_N 8
#define MB 8

#define TPX 16                     // pixels (columns) per block
#define SXW 18                     // staged cols = TPX + 2 halo
#define SXSZ (IN_C * 3 * SXW)      // 1728 words = 6.9 KB
#define W2SZ (Q_N * P_N * MB)      // 2304 words = 9.2 KB

__global__ __launch_bounds__(THREADS, 8)
void morr_conv_kernel(const float* __restrict__ x,
                      const float* __restrict__ weight,
                      const float* __restrict__ mos,
                      float* __restrict__ out)
{
    __shared__ float sx[SXSZ];     // raw squared inputs [c][r3][col18]
    __shared__ float w2[W2SZ];     // [q][p][m]
    __shared__ float slds[Q_N];    // signed scale * E

    const int tid = threadIdx.x;
    const int blk = blockIdx.x;
    const int b    = blk >> 8;          // image (256 blocks per image)
    const int rem  = blk & 255;
    const int row  = rem >> 2;          // output row 0..63
    const int w0   = (rem & 3) << 4;    // col-tile origin: 0,16,32,48

    const float GAIN   = 1.6666666666666667f;   // 100/36 applied to x^2
    const float INV2PI = 0.15915494309189535f;

    // mrr_tr algebra: tr = (S-c)/(D-c) = 1 + E/(D-c), c = C2*cos(phi).
    // Q even => sum_q sc_q = 0 exactly => out = sum_q sc_q*E * rcp(D-c).
    const float A_ = 0.8578f, R_ = 0.8985f;
    const float S_ = A_ * A_ + R_ * R_;
    const float D_ = 1.f + (A_ * R_) * (A_ * R_);
    const float C2 = 2.f * A_ * R_;
    const float E_ = S_ - D_;

    // ---- stage squared inputs: rows row-1..row+1, cols w0-1..w0+16 ----
    for (int idx = tid; idx < SXSZ; idx += THREADS) {
        int c    = idx / (3 * SXW);
        int rem2 = idx - c * (3 * SXW);
        int r    = rem2 / SXW;
        int col  = rem2 - r * SXW;
        int gh = row + r - 1;
        int gw = w0 + col - 1;
        float v = 0.f;
        if ((unsigned)gh < 64u && (unsigned)gw < 64u)
            v = x[((b * IN_C + c) * HW + gh) * HW + gw];
        sx[idx] = GAIN * v * v;
    }
    // ---- stage weights as [q][p][m], folded by 1/(2*pi) ----
    for (int idx = tid; idx < W2SZ; idx += THREADS) {
        int p    = idx / (Q_N * MB);
        int rem2 = idx - p * (Q_N * MB);
        int q    = rem2 >> 3;
        int m    = idx & 7;
        w2[(q * P_N + p) * MB + m] = weight[idx] * INV2PI;
    }
    // ---- signed scale, E folded in ----
    if (tid < Q_N)
        slds[tid] = ((tid < 18) ? mos[tid] : -mos[tid - 18]) * E_;
    __syncthreads();

    const int px = tid & 15;          // pixel column within tile
    const int p  = (tid >> 4) & 7;    // output channel-block
    const int kh = tid >> 7;          // k-half: 0 -> k=0..3, 1 -> k=4..7

    float acc[4];
#pragma unroll
    for (int i = 0; i < 4; ++i) acc[i] = 0.f;

    const float4* w4 = (const float4*)w2;

#pragma unroll 1
    for (int z = 0; z < 4; ++z) {
        const int sbase = (z * 8) * (3 * SXW) + px;
        const int qz = z * 9;
#pragma unroll
        for (int qi = 0; qi < 9; ++qi) {
            // im2col gather: u = qi*8+j in [0,72), cu=u/9, r=u%9 (compile-time)
            float iv[8];
#pragma unroll
            for (int j = 0; j < 8; ++j) {
                const int u  = qi * 8 + j;
                const int cu = u / 9;
                const int r  = u - cu * 9;
                const int ki = r / 3;
                const int kj = r - ki * 3;
                iv[j] = sx[sbase + cu * (3 * SXW) + ki * SXW + kj];
            }
            const float sc = slds[qz + qi];

            // weights for (q,p), k-half swapped: wv[m] = w[m ^ 4*kh]
            // since (kh*4+kk-j)&7 == ((kk-j)&7) ^ (4*kh)
            const int wq = ((qz + qi) * P_N + p) * 2;
            float4 wa = w4[wq + kh];
            float4 wb = w4[wq + 1 - kh];
            float wv[8] = {wa.x, wa.y, wa.z, wa.w, wb.x, wb.y, wb.z, wb.w};

            float ph[4];
#pragma unroll
            for (int kk = 0; kk < 4; ++kk) ph[kk] = iv[0] * wv[kk];
#pragma unroll
            for (int j = 1; j < 8; ++j) {
#pragma unroll
                for (int kk = 0; kk < 4; ++kk)
                    ph[kk] = fmaf(iv[j], wv[(kk - j) & 7], ph[kk]);
            }
#pragma unroll
            for (int kk = 0; kk < 4; ++kk) {
                float cc = __builtin_amdgcn_cosf(ph[kk]);   // phi in revolutions
                float d  = fmaf(-C2, cc, D_);
                acc[kk] = fmaf(sc, __builtin_amdgcn_rcpf(d), acc[kk]);
            }
        }
    }

    // ---- store: oc = p*8 + kh*4 + kk ----
    float* op = out + ((b * OUT_C + p * MB + kh * 4) * (HW * HW)) + row * HW + w0 + px;
#pragma unroll
    for (int kk = 0; kk < 4; ++kk)
        op[kk * (HW * HW)] = acc[kk];
}

extern "C" void kernel_launch(void* const* d_in, const int* in_sizes, int n_in,
                              void* d_out, int out_size, void* d_ws, size_t ws_size,
                              hipStream_t stream) {
    const float* x      = (const float*)d_in[0];
    const float* weight = (const float*)d_in[1];
    const float* mos    = (const float*)d_in[2];
    float* out = (float*)d_out;

    // 8 images x 64 rows x 4 col-tiles of 16 pixels
    dim3 grid(2048), block(THREADS);
    hipLaunchKernelGGL(morr_conv_kernel, grid, block, 0, stream, x, weight, mos, out);
}